// Round 1
// baseline (9395.097 us; speedup 1.0000x reference)
//
#include <hip/hip_runtime.h>
#include <hip/hip_bf16.h>

#define NN 100000
#define NE 1600000
#define FD 128
#define NG 64
#define NL 3

// ---------------- degree / norm ----------------
__global__ __launch_bounds__(256) void k_deg_init(float* deg) {
    int i = blockIdx.x * 256 + threadIdx.x;
    if (i < NN) deg[i] = 1.0f;  // self-loop contributes 1
}

__global__ __launch_bounds__(256) void k_deg_edges(const int* __restrict__ col, float* deg) {
    int e = blockIdx.x * 256 + threadIdx.x;
    if (e < NE) unsafeAtomicAdd(&deg[col[e]], 1.0f);
}

__global__ __launch_bounds__(256) void k_dinv(float* deg) {
    int i = blockIdx.x * 256 + threadIdx.x;
    if (i < NN) deg[i] = 1.0f / sqrtf(deg[i]);   // deg >= 1 always
}

// ---------------- GEMM: C[n][128] = A[n][128] @ W[128][128] ----------------
// block: 256 threads, 128 rows/block. thread tile 8x8.
// LDS: W k-chunk [32][128] (16KB) + A tile [128][33] padded (16.9KB).
__global__ __launch_bounds__(256) void k_gemm(const float* __restrict__ A,
                                              const float* __restrict__ W,
                                              float* __restrict__ C, int n) {
    __shared__ float hs[128][33];
    __shared__ float ws[32][128];
    int t  = threadIdx.x;
    int r0 = blockIdx.x * 128;
    int tr = t >> 4;    // 0..15 -> rows tr*8..tr*8+7
    int tc = t & 15;    // 0..15 -> cols tc + 16*j
    float acc[8][8];
#pragma unroll
    for (int i = 0; i < 8; ++i)
#pragma unroll
        for (int j = 0; j < 8; ++j) acc[i][j] = 0.0f;

    int rows = n - r0; if (rows > 128) rows = 128;

    for (int kc = 0; kc < 4; ++kc) {
        // stage A tile chunk: 128 rows x 32 k  (1024 float4, 4 per thread)
#pragma unroll
        for (int it = 0; it < 4; ++it) {
            int idx = t + 256 * it;      // 0..1023
            int rr  = idx >> 3;          // 0..127
            int k4  = idx & 7;           // 0..7
            float4 v = make_float4(0.f, 0.f, 0.f, 0.f);
            if (rr < rows)
                v = *(const float4*)(A + (size_t)(r0 + rr) * FD + kc * 32 + k4 * 4);
            hs[rr][k4 * 4 + 0] = v.x;
            hs[rr][k4 * 4 + 1] = v.y;
            hs[rr][k4 * 4 + 2] = v.z;
            hs[rr][k4 * 4 + 3] = v.w;
        }
        // stage W chunk: 32 k x 128 c (1024 float4, 4 per thread)
#pragma unroll
        for (int it = 0; it < 4; ++it) {
            int idx = t + 256 * it;      // 0..1023
            int kk  = idx >> 5;          // 0..31
            int c4  = idx & 31;          // 0..31
            *(float4*)(&ws[kk][c4 * 4]) =
                *(const float4*)(W + (size_t)(kc * 32 + kk) * FD + c4 * 4);
        }
        __syncthreads();
#pragma unroll 4
        for (int k = 0; k < 32; ++k) {
            float a[8];
#pragma unroll
            for (int i = 0; i < 8; ++i) a[i] = hs[tr * 8 + i][k];
#pragma unroll
            for (int j = 0; j < 8; ++j) {
                float b = ws[k][tc + 16 * j];
#pragma unroll
                for (int i = 0; i < 8; ++i) acc[i][j] = fmaf(a[i], b, acc[i][j]);
            }
        }
        __syncthreads();
    }
#pragma unroll
    for (int i = 0; i < 8; ++i) {
        int r = r0 + tr * 8 + i;
        if (r < n) {
#pragma unroll
            for (int j = 0; j < 8; ++j)
                C[(size_t)r * FD + tc + 16 * j] = acc[i][j];
        }
    }
}

// ---------------- self-loop init: agg = hw * dinv^2 ----------------
__global__ __launch_bounds__(256) void k_selfinit(const float* __restrict__ hw,
                                                  const float* __restrict__ dinv,
                                                  float* __restrict__ agg) {
    int tid = blockIdx.x * 256 + threadIdx.x;   // NN*32 float4s
    if (tid >= NN * 32) return;
    int node = tid >> 5;
    float di = dinv[node];
    float s = di * di;
    float4 v = ((const float4*)hw)[tid];
    v.x *= s; v.y *= s; v.z *= s; v.w *= s;
    ((float4*)agg)[tid] = v;
}

// ---------------- edge scatter: agg[col] += hw[row] * dinv[row]*dinv[col] ----------------
__global__ __launch_bounds__(256) void k_scatter(const int* __restrict__ row,
                                                 const int* __restrict__ col,
                                                 const float* __restrict__ dinv,
                                                 const float* __restrict__ hw,
                                                 float* __restrict__ agg) {
    long long tid = (long long)blockIdx.x * 256 + threadIdx.x;
    if (tid >= (long long)NE * 32) return;
    int e  = (int)(tid >> 5);
    int f4 = (int)(tid & 31);
    int r = row[e], c = col[e];
    float nrm = dinv[r] * dinv[c];
    float4 v = ((const float4*)(hw + (size_t)r * FD))[f4];
    float* dst = agg + (size_t)c * FD + f4 * 4;
    unsafeAtomicAdd(dst + 0, v.x * nrm);
    unsafeAtomicAdd(dst + 1, v.y * nrm);
    unsafeAtomicAdd(dst + 2, v.z * nrm);
    unsafeAtomicAdd(dst + 3, v.w * nrm);
}

// ---------------- relu(agg + bias) in place ----------------
__global__ __launch_bounds__(256) void k_relu_bias(float* __restrict__ h,
                                                   const float* __restrict__ b) {
    int tid = blockIdx.x * 256 + threadIdx.x;   // NN*32 float4s
    if (tid >= NN * 32) return;
    int f4 = tid & 31;
    float4 v = ((float4*)h)[tid];
    float4 bb = ((const float4*)b)[f4];
    v.x = fmaxf(v.x + bb.x, 0.f);
    v.y = fmaxf(v.y + bb.y, 0.f);
    v.z = fmaxf(v.z + bb.z, 0.f);
    v.w = fmaxf(v.w + bb.w, 0.f);
    ((float4*)h)[tid] = v;
}

// ---------------- mean pool (atomic sums) ----------------
__global__ __launch_bounds__(256) void k_pool(const float* __restrict__ h,
                                              const int* __restrict__ batch,
                                              float* __restrict__ pool,
                                              float* __restrict__ cnt) {
    int tid = blockIdx.x * 256 + threadIdx.x;   // NN*32
    if (tid >= NN * 32) return;
    int node = tid >> 5, f4 = tid & 31;
    int g = batch[node];
    float4 v = ((const float4*)h)[tid];
    float* dst = pool + (size_t)g * FD + f4 * 4;
    unsafeAtomicAdd(dst + 0, v.x);
    unsafeAtomicAdd(dst + 1, v.y);
    unsafeAtomicAdd(dst + 2, v.z);
    unsafeAtomicAdd(dst + 3, v.w);
    if (f4 == 0) unsafeAtomicAdd(&cnt[g], 1.0f);
}

// ---------------- MLP head ----------------
__global__ __launch_bounds__(128) void k_mlp(const float* __restrict__ pool,
                                             const float* __restrict__ cnt,
                                             const float* __restrict__ W1,
                                             const float* __restrict__ b1,
                                             const float* __restrict__ W2,
                                             const float* __restrict__ b2,
                                             float* __restrict__ out) {
    int g = blockIdx.x, j = threadIdx.x;
    __shared__ float gm[FD];
    float c = fmaxf(cnt[g], 1.0f);
    gm[j] = pool[(size_t)g * FD + j] / c;
    __syncthreads();
    float v = b1[j];
#pragma unroll 8
    for (int k = 0; k < FD; ++k) v = fmaf(gm[k], W1[(size_t)k * FD + j], v);
    v = fmaxf(v, 0.f);
    float p = v * W2[j];
#pragma unroll
    for (int off = 32; off; off >>= 1) p += __shfl_down(p, off);
    __shared__ float part[2];
    if ((j & 63) == 0) part[j >> 6] = p;
    __syncthreads();
    if (j == 0) out[g] = part[0] + part[1] + b2[0];
}

extern "C" void kernel_launch(void* const* d_in, const int* in_sizes, int n_in,
                              void* d_out, int out_size, void* d_ws, size_t ws_size,
                              hipStream_t stream) {
    const float* x     = (const float*)d_in[0];
    const int*   ei    = (const int*)d_in[1];    // [2][NE]
    const int*   batch = (const int*)d_in[2];
    const float* convW = (const float*)d_in[3];  // [3][128][128]
    const float* convB = (const float*)d_in[4];  // [3][128]
    const float* linW1 = (const float*)d_in[5];
    const float* linB1 = (const float*)d_in[6];
    const float* linW2 = (const float*)d_in[7];
    const float* linB2 = (const float*)d_in[8];
    float* out = (float*)d_out;

    char* ws = (char*)d_ws;
    float* dinv = (float*)ws;                                          // NN f32
    float* buf0 = (float*)(ws + ((size_t)1 << 20));                    // NN*FD f32 (51.2MB)
    float* buf1 = (float*)(ws + ((size_t)1 << 20) + ((size_t)52 << 20));
    float* pool = (float*)(ws + ((size_t)1 << 20) + ((size_t)104 << 20));
    float* cnt  = pool + NG * FD;

    const int* row = ei;        // sources
    const int* col = ei + NE;   // targets

    k_deg_init<<<(NN + 255) / 256, 256, 0, stream>>>(dinv);
    k_deg_edges<<<(NE + 255) / 256, 256, 0, stream>>>(col, dinv);
    k_dinv<<<(NN + 255) / 256, 256, 0, stream>>>(dinv);

    const float* h = x;
    for (int l = 0; l < NL; ++l) {
        k_gemm<<<(NN + 127) / 128, 256, 0, stream>>>(h, convW + (size_t)l * FD * FD, buf0, NN);
        k_selfinit<<<(NN * 32 + 255) / 256, 256, 0, stream>>>(buf0, dinv, buf1);
        long long nt = (long long)NE * 32;
        k_scatter<<<(int)((nt + 255) / 256), 256, 0, stream>>>(row, col, dinv, buf0, buf1);
        k_relu_bias<<<(NN * 32 + 255) / 256, 256, 0, stream>>>(buf1, convB + (size_t)l * FD);
        h = buf1;
    }

    hipMemsetAsync(pool, 0, (size_t)(NG * FD + NG) * sizeof(float), stream);
    k_pool<<<(NN * 32 + 255) / 256, 256, 0, stream>>>(h, batch, pool, cnt);
    k_mlp<<<NG, 128, 0, stream>>>(pool, cnt, linW1, linB1, linW2, linB2, out);
}

// Round 5
// 870.924 us; speedup vs baseline: 10.7875x; 10.7875x over previous
//
#include <hip/hip_runtime.h>
#include <hip/hip_bf16.h>

#define NN 100000
#define NE 1600000
#define FD 128
#define NG 64
#define NL 3
#define NB_SCAN 391   // ceil(NN/256)

// ---------------- CSR build: histogram ----------------
__global__ __launch_bounds__(256) void k_hist(const int* __restrict__ col, int* __restrict__ degi) {
    int e = blockIdx.x * 256 + threadIdx.x;
    if (e < NE) atomicAdd(&degi[col[e]], 1);
}

// dinv[i] = 1/sqrt(deg_i + 1)  (self-loop included)
__global__ __launch_bounds__(256) void k_dinv(const int* __restrict__ degi, float* __restrict__ dinv) {
    int i = blockIdx.x * 256 + threadIdx.x;
    if (i < NN) dinv[i] = 1.0f / sqrtf((float)(degi[i] + 1));
}

// ---------------- 3-pass exclusive scan of degi -> start/cursor ----------------
__global__ __launch_bounds__(256) void k_scanA(const int* __restrict__ degi, int* __restrict__ partial) {
    __shared__ int sd[256];
    int t = threadIdx.x;
    int i = blockIdx.x * 256 + t;
    sd[t] = (i < NN) ? degi[i] : 0;
    __syncthreads();
#pragma unroll
    for (int off = 128; off; off >>= 1) {
        if (t < off) sd[t] += sd[t + off];
        __syncthreads();
    }
    if (t == 0) partial[blockIdx.x] = sd[0];
}

__global__ __launch_bounds__(512) void k_scanB(int* __restrict__ partial) {
    __shared__ int sd[512];
    int t = threadIdx.x;
    int v = (t < NB_SCAN) ? partial[t] : 0;
    sd[t] = v;
    __syncthreads();
    for (int off = 1; off < 512; off <<= 1) {
        int x = (t >= off) ? sd[t - off] : 0;
        __syncthreads();
        sd[t] += x;
        __syncthreads();
    }
    if (t < NB_SCAN) partial[t] = sd[t] - v;   // exclusive
}

__global__ __launch_bounds__(256) void k_scanC(const int* __restrict__ degi,
                                               const int* __restrict__ blockoff,
                                               int* __restrict__ start, int* __restrict__ cursor) {
    __shared__ int sd[256];
    int t = threadIdx.x;
    int i = blockIdx.x * 256 + t;
    int v = (i < NN) ? degi[i] : 0;
    sd[t] = v;
    __syncthreads();
    for (int off = 1; off < 256; off <<= 1) {
        int x = (t >= off) ? sd[t - off] : 0;
        __syncthreads();
        sd[t] += x;
        __syncthreads();
    }
    int ex = sd[t] - v + blockoff[blockIdx.x];
    if (i < NN) { start[i] = ex; cursor[i] = ex; }
}

__global__ __launch_bounds__(256) void k_fill(const int* __restrict__ row, const int* __restrict__ col,
                                              int* __restrict__ cursor, int* __restrict__ csr_src) {
    int e = blockIdx.x * 256 + threadIdx.x;
    if (e < NE) {
        int c = col[e];
        int p = atomicAdd(&cursor[c], 1);
        csr_src[p] = row[e];
    }
}

// ---------------- GEMM: C[n][128] = (A[n][128] @ W[128][128]) * dinv[n] ----------------
__global__ __launch_bounds__(256) void k_gemm(const float* __restrict__ A,
                                              const float* __restrict__ W,
                                              const float* __restrict__ dinv,
                                              float* __restrict__ C, int n) {
    __shared__ float hs[128][33];
    __shared__ float ws[32][128];
    int t  = threadIdx.x;
    int r0 = blockIdx.x * 128;
    int tr = t >> 4;
    int tc = t & 15;
    float acc[8][8];
#pragma unroll
    for (int i = 0; i < 8; ++i)
#pragma unroll
        for (int j = 0; j < 8; ++j) acc[i][j] = 0.0f;

    int rows = n - r0; if (rows > 128) rows = 128;

    for (int kc = 0; kc < 4; ++kc) {
#pragma unroll
        for (int it = 0; it < 4; ++it) {
            int idx = t + 256 * it;
            int rr  = idx >> 3;
            int k4  = idx & 7;
            float4 v = make_float4(0.f, 0.f, 0.f, 0.f);
            if (rr < rows)
                v = *(const float4*)(A + (size_t)(r0 + rr) * FD + kc * 32 + k4 * 4);
            hs[rr][k4 * 4 + 0] = v.x;
            hs[rr][k4 * 4 + 1] = v.y;
            hs[rr][k4 * 4 + 2] = v.z;
            hs[rr][k4 * 4 + 3] = v.w;
        }
#pragma unroll
        for (int it = 0; it < 4; ++it) {
            int idx = t + 256 * it;
            int kk  = idx >> 5;
            int c4  = idx & 31;
            *(float4*)(&ws[kk][c4 * 4]) =
                *(const float4*)(W + (size_t)(kc * 32 + kk) * FD + c4 * 4);
        }
        __syncthreads();
#pragma unroll 4
        for (int k = 0; k < 32; ++k) {
            float a[8];
#pragma unroll
            for (int i = 0; i < 8; ++i) a[i] = hs[tr * 8 + i][k];
#pragma unroll
            for (int j = 0; j < 8; ++j) {
                float b = ws[k][tc + 16 * j];
#pragma unroll
                for (int i = 0; i < 8; ++i) acc[i][j] = fmaf(a[i], b, acc[i][j]);
            }
        }
        __syncthreads();
    }
#pragma unroll
    for (int i = 0; i < 8; ++i) {
        int r = r0 + tr * 8 + i;
        if (r < n) {
            float d = dinv[r];
#pragma unroll
            for (int j = 0; j < 8; ++j)
                C[(size_t)r * FD + tc + 16 * j] = acc[i][j] * d;
        }
    }
}

// ---------------- gather-aggregate: h[c] = relu(dinv[c]*(hw'[c] + sum_in hw'[src]) + b) ----------------
// one wave (64 lanes) per node, float2 per lane.
__global__ __launch_bounds__(256) void k_gather(const float* __restrict__ hwp,
                                                const int* __restrict__ start,
                                                const int* __restrict__ csr_src,
                                                const float* __restrict__ dinv,
                                                const float* __restrict__ bias,
                                                float* __restrict__ out) {
    int node = blockIdx.x * 4 + (threadIdx.x >> 6);
    if (node >= NN) return;
    int lane = threadIdx.x & 63;

    float2 acc = *(const float2*)(hwp + (size_t)node * FD + lane * 2);  // self term
    int s0 = start[node];
    int s1 = (node < NN - 1) ? start[node + 1] : NE;

    for (int base = s0; base < s1; base += 64) {
        int n = s1 - base; if (n > 64) n = 64;
        int idx = 0;
        if (lane < n) idx = csr_src[base + lane];
        for (int i = 0; i < n; ++i) {
            int s = __shfl(idx, i);
            float2 v = *(const float2*)(hwp + (size_t)s * FD + lane * 2);
            acc.x += v.x;
            acc.y += v.y;
        }
    }
    float d = dinv[node];
    float2 b = *(const float2*)(bias + lane * 2);
    float2 o;
    o.x = fmaxf(fmaf(acc.x, d, b.x), 0.f);
    o.y = fmaxf(fmaf(acc.y, d, b.y), 0.f);
    *(float2*)(out + (size_t)node * FD + lane * 2) = o;
}

// ---------------- mean pool: register run-accumulate + LDS slots + few global atomics ----------------
__global__ __launch_bounds__(256) void k_pool(const float* __restrict__ h,
                                              const int* __restrict__ batch,
                                              float* __restrict__ pool,
                                              int* __restrict__ cnt) {
    __shared__ float lacc[8][128];
    __shared__ int   lcnt[8];
    int t  = threadIdx.x;
    int f4 = t & 31;
    int r  = t >> 5;
    int base = blockIdx.x * 256;

    for (int i = t; i < 8 * 128; i += 256) ((float*)lacc)[i] = 0.f;
    if (t < 8) lcnt[t] = 0;
    __syncthreads();

    int g0 = batch[base];
    int lastnode = base + 255; if (lastnode >= NN) lastnode = NN - 1;
    int span = batch[lastnode] - g0 + 1;

    float4 acc = make_float4(0.f, 0.f, 0.f, 0.f);
    int curg = -1, ccount = 0;
    for (int k = 0; k < 32; ++k) {
        int node = base + (k << 3) + r;
        if (node >= NN) break;
        int g = batch[node];
        float4 v = ((const float4*)h)[(size_t)node * 32 + f4];
        if (g != curg) {
            if (curg >= 0) {
                int s = curg - g0;
                if (s < 8) {
                    atomicAdd(&lacc[s][f4 * 4 + 0], acc.x);
                    atomicAdd(&lacc[s][f4 * 4 + 1], acc.y);
                    atomicAdd(&lacc[s][f4 * 4 + 2], acc.z);
                    atomicAdd(&lacc[s][f4 * 4 + 3], acc.w);
                    if (f4 == 0) atomicAdd(&lcnt[s], ccount);
                } else {
                    float* dst = pool + (size_t)curg * FD + f4 * 4;
                    unsafeAtomicAdd(dst + 0, acc.x);
                    unsafeAtomicAdd(dst + 1, acc.y);
                    unsafeAtomicAdd(dst + 2, acc.z);
                    unsafeAtomicAdd(dst + 3, acc.w);
                    if (f4 == 0) atomicAdd(&cnt[curg], ccount);
                }
            }
            curg = g; acc = make_float4(0.f, 0.f, 0.f, 0.f); ccount = 0;
        }
        acc.x += v.x; acc.y += v.y; acc.z += v.z; acc.w += v.w;
        ccount++;
    }
    if (curg >= 0) {
        int s = curg - g0;
        if (s < 8) {
            atomicAdd(&lacc[s][f4 * 4 + 0], acc.x);
            atomicAdd(&lacc[s][f4 * 4 + 1], acc.y);
            atomicAdd(&lacc[s][f4 * 4 + 2], acc.z);
            atomicAdd(&lacc[s][f4 * 4 + 3], acc.w);
            if (f4 == 0) atomicAdd(&lcnt[s], ccount);
        } else {
            float* dst = pool + (size_t)curg * FD + f4 * 4;
            unsafeAtomicAdd(dst + 0, acc.x);
            unsafeAtomicAdd(dst + 1, acc.y);
            unsafeAtomicAdd(dst + 2, acc.z);
            unsafeAtomicAdd(dst + 3, acc.w);
            if (f4 == 0) atomicAdd(&cnt[curg], ccount);
        }
    }
    __syncthreads();
    if (span > 8) span = 8;
    for (int s = 0; s < span; ++s) {
        for (int i = t; i < 128; i += 256)
            unsafeAtomicAdd(&pool[(size_t)(g0 + s) * FD + i], lacc[s][i]);
        if (t == 0 && lcnt[s]) atomicAdd(&cnt[g0 + s], lcnt[s]);
    }
}

// ---------------- MLP head ----------------
__global__ __launch_bounds__(128) void k_mlp(const float* __restrict__ pool,
                                             const int* __restrict__ cnt,
                                             const float* __restrict__ W1,
                                             const float* __restrict__ b1,
                                             const float* __restrict__ W2,
                                             const float* __restrict__ b2,
                                             float* __restrict__ out) {
    int g = blockIdx.x, j = threadIdx.x;
    __shared__ float gm[FD];
    float c = fmaxf((float)cnt[g], 1.0f);
    gm[j] = pool[(size_t)g * FD + j] / c;
    __syncthreads();
    float v = b1[j];
#pragma unroll 8
    for (int k = 0; k < FD; ++k) v = fmaf(gm[k], W1[(size_t)k * FD + j], v);
    v = fmaxf(v, 0.f);
    float p = v * W2[j];
#pragma unroll
    for (int off = 32; off; off >>= 1) p += __shfl_down(p, off);
    __shared__ float part[2];
    if ((j & 63) == 0) part[j >> 6] = p;
    __syncthreads();
    if (j == 0) out[g] = part[0] + part[1] + b2[0];
}

extern "C" void kernel_launch(void* const* d_in, const int* in_sizes, int n_in,
                              void* d_out, int out_size, void* d_ws, size_t ws_size,
                              hipStream_t stream) {
    const float* x     = (const float*)d_in[0];
    const int*   ei    = (const int*)d_in[1];    // [2][NE]
    const int*   batch = (const int*)d_in[2];
    const float* convW = (const float*)d_in[3];
    const float* convB = (const float*)d_in[4];
    const float* linW1 = (const float*)d_in[5];
    const float* linB1 = (const float*)d_in[6];
    const float* linW2 = (const float*)d_in[7];
    const float* linB2 = (const float*)d_in[8];
    float* out = (float*)d_out;

    char* ws = (char*)d_ws;
    // layout (compact, ~113.1 MB total)
    int*   degi    = (int*)ws;                                   // NN ints
    float* dinv    = (float*)(ws + 400 * 1024);
    int*   start   = (int*)(ws + 800 * 1024);                    // NN ints
    int*   cursor  = (int*)(ws + 1200 * 1024);                   // NN ints
    int*   partial = (int*)(ws + 1600 * 1024);                   // 512 ints
    int*   csr_src = (int*)(ws + ((size_t)2 << 20));             // NE ints (6.4MB)
    float* buf0    = (float*)(ws + ((size_t)9 << 20));           // 51.2MB
    float* buf1    = (float*)(ws + ((size_t)61 << 20));          // 51.2MB
    float* pool    = (float*)(ws + ((size_t)113 << 20));         // NG*FD
    int*   cnt     = (int*)(pool + NG * FD);

    const int* row = ei;        // sources
    const int* col = ei + NE;   // targets

    // CSR build + norms
    hipMemsetAsync(degi, 0, NN * sizeof(int), stream);
    k_hist<<<(NE + 255) / 256, 256, 0, stream>>>(col, degi);
    k_dinv<<<(NN + 255) / 256, 256, 0, stream>>>(degi, dinv);
    k_scanA<<<NB_SCAN, 256, 0, stream>>>(degi, partial);
    k_scanB<<<1, 512, 0, stream>>>(partial);
    k_scanC<<<NB_SCAN, 256, 0, stream>>>(degi, partial, start, cursor);
    k_fill<<<(NE + 255) / 256, 256, 0, stream>>>(row, col, cursor, csr_src);

    const float* h = x;
    for (int l = 0; l < NL; ++l) {
        k_gemm<<<(NN + 127) / 128, 256, 0, stream>>>(h, convW + (size_t)l * FD * FD, dinv, buf0, NN);
        k_gather<<<(NN + 3) / 4, 256, 0, stream>>>(buf0, start, csr_src, dinv,
                                                   convB + (size_t)l * FD, buf1);
        h = buf1;
    }

    hipMemsetAsync(pool, 0, (size_t)(NG * FD) * sizeof(float) + NG * sizeof(int), stream);
    k_pool<<<(NN + 255) / 256, 256, 0, stream>>>(h, batch, pool, cnt);
    k_mlp<<<NG, 128, 0, stream>>>(pool, cnt, linW1, linB1, linW2, linB2, out);
}

// Round 6
// 683.646 us; speedup vs baseline: 13.7426x; 1.2739x over previous
//
#include <hip/hip_runtime.h>
#include <hip/hip_bf16.h>
#include <hip/hip_fp16.h>

#define NN 100000
#define NE 1600000
#define FD 128
#define NG 64
#define NL 3
#define NB_SCAN 391   // ceil(NN/256)

// ---------------- CSR build: histogram ----------------
__global__ __launch_bounds__(256) void k_hist(const int* __restrict__ col, int* __restrict__ degi) {
    int e = blockIdx.x * 256 + threadIdx.x;
    if (e < NE) atomicAdd(&degi[col[e]], 1);
}

// dinv[i] = 1/sqrt(deg_i + 1)  (self-loop included)
__global__ __launch_bounds__(256) void k_dinv(const int* __restrict__ degi, float* __restrict__ dinv) {
    int i = blockIdx.x * 256 + threadIdx.x;
    if (i < NN) dinv[i] = 1.0f / sqrtf((float)(degi[i] + 1));
}

// ---------------- 3-pass exclusive scan of degi -> start/cursor ----------------
__global__ __launch_bounds__(256) void k_scanA(const int* __restrict__ degi, int* __restrict__ partial) {
    __shared__ int sd[256];
    int t = threadIdx.x;
    int i = blockIdx.x * 256 + t;
    sd[t] = (i < NN) ? degi[i] : 0;
    __syncthreads();
#pragma unroll
    for (int off = 128; off; off >>= 1) {
        if (t < off) sd[t] += sd[t + off];
        __syncthreads();
    }
    if (t == 0) partial[blockIdx.x] = sd[0];
}

__global__ __launch_bounds__(512) void k_scanB(int* __restrict__ partial) {
    __shared__ int sd[512];
    int t = threadIdx.x;
    int v = (t < NB_SCAN) ? partial[t] : 0;
    sd[t] = v;
    __syncthreads();
    for (int off = 1; off < 512; off <<= 1) {
        int x = (t >= off) ? sd[t - off] : 0;
        __syncthreads();
        sd[t] += x;
        __syncthreads();
    }
    if (t < NB_SCAN) partial[t] = sd[t] - v;   // exclusive
}

__global__ __launch_bounds__(256) void k_scanC(const int* __restrict__ degi,
                                               const int* __restrict__ blockoff,
                                               int* __restrict__ start, int* __restrict__ cursor) {
    __shared__ int sd[256];
    int t = threadIdx.x;
    int i = blockIdx.x * 256 + t;
    int v = (i < NN) ? degi[i] : 0;
    sd[t] = v;
    __syncthreads();
    for (int off = 1; off < 256; off <<= 1) {
        int x = (t >= off) ? sd[t - off] : 0;
        __syncthreads();
        sd[t] += x;
        __syncthreads();
    }
    int ex = sd[t] - v + blockoff[blockIdx.x];
    if (i < NN) { start[i] = ex; cursor[i] = ex; }
}

__global__ __launch_bounds__(256) void k_fill(const int* __restrict__ row, const int* __restrict__ col,
                                              int* __restrict__ cursor, int* __restrict__ csr_src) {
    int e = blockIdx.x * 256 + threadIdx.x;
    if (e < NE) {
        int c = col[e];
        int p = atomicAdd(&cursor[c], 1);
        csr_src[p] = row[e];
    }
}

// ---------------- GEMM: C16[n][128] = half((A[n][128] @ W[128][128]) * dinv[n]) ----------------
__global__ __launch_bounds__(256) void k_gemm(const float* __restrict__ A,
                                              const float* __restrict__ W,
                                              const float* __restrict__ dinv,
                                              __half* __restrict__ C16, int n) {
    __shared__ float hs[128][33];
    __shared__ float ws[32][128];
    int t  = threadIdx.x;
    int r0 = blockIdx.x * 128;
    int tr = t >> 4;
    int tc = t & 15;
    float acc[8][8];
#pragma unroll
    for (int i = 0; i < 8; ++i)
#pragma unroll
        for (int j = 0; j < 8; ++j) acc[i][j] = 0.0f;

    int rows = n - r0; if (rows > 128) rows = 128;

    for (int kc = 0; kc < 4; ++kc) {
#pragma unroll
        for (int it = 0; it < 4; ++it) {
            int idx = t + 256 * it;
            int rr  = idx >> 3;
            int k4  = idx & 7;
            float4 v = make_float4(0.f, 0.f, 0.f, 0.f);
            if (rr < rows)
                v = *(const float4*)(A + (size_t)(r0 + rr) * FD + kc * 32 + k4 * 4);
            hs[rr][k4 * 4 + 0] = v.x;
            hs[rr][k4 * 4 + 1] = v.y;
            hs[rr][k4 * 4 + 2] = v.z;
            hs[rr][k4 * 4 + 3] = v.w;
        }
#pragma unroll
        for (int it = 0; it < 4; ++it) {
            int idx = t + 256 * it;
            int kk  = idx >> 5;
            int c4  = idx & 31;
            *(float4*)(&ws[kk][c4 * 4]) =
                *(const float4*)(W + (size_t)(kc * 32 + kk) * FD + c4 * 4);
        }
        __syncthreads();
#pragma unroll 4
        for (int k = 0; k < 32; ++k) {
            float a[8];
#pragma unroll
            for (int i = 0; i < 8; ++i) a[i] = hs[tr * 8 + i][k];
#pragma unroll
            for (int j = 0; j < 8; ++j) {
                float b = ws[k][tc + 16 * j];
#pragma unroll
                for (int i = 0; i < 8; ++i) acc[i][j] = fmaf(a[i], b, acc[i][j]);
            }
        }
        __syncthreads();
    }
#pragma unroll
    for (int i = 0; i < 8; ++i) {
        int r = r0 + tr * 8 + i;
        if (r < n) {
            float d = dinv[r];
#pragma unroll
            for (int j = 0; j < 8; ++j)
                C16[(size_t)r * FD + tc + 16 * j] = __float2half(acc[i][j] * d);
        }
    }
}

// ---------------- gather-aggregate: h[c] = relu(dinv[c]*(hw'[c] + sum_in hw'[src]) + b) ----------------
// one wave per node, half2 per lane, scalar (wave-uniform) CSR index loads, 4-way ILP unroll.
__global__ __launch_bounds__(256) void k_gather(const __half2* __restrict__ hw16,
                                                const int* __restrict__ start,
                                                const int* __restrict__ csr_src,
                                                const float* __restrict__ dinv,
                                                const float* __restrict__ bias,
                                                float* __restrict__ out) {
    int node = blockIdx.x * 4 + (threadIdx.x >> 6);
    if (node >= NN) return;
    int lane = threadIdx.x & 63;

    int p  = __builtin_amdgcn_readfirstlane(start[node]);
    int pe = __builtin_amdgcn_readfirstlane((node < NN - 1) ? start[node + 1] : NE);

    float2 a0 = __half22float2(hw16[(size_t)node * 64 + lane]);  // self term
    float2 a1 = make_float2(0.f, 0.f);
    float2 a2 = make_float2(0.f, 0.f);
    float2 a3 = make_float2(0.f, 0.f);

    for (; p + 4 <= pe; p += 4) {
        int e0 = csr_src[p + 0];
        int e1 = csr_src[p + 1];
        int e2 = csr_src[p + 2];
        int e3 = csr_src[p + 3];
        float2 v0 = __half22float2(hw16[(size_t)e0 * 64 + lane]);
        float2 v1 = __half22float2(hw16[(size_t)e1 * 64 + lane]);
        float2 v2 = __half22float2(hw16[(size_t)e2 * 64 + lane]);
        float2 v3 = __half22float2(hw16[(size_t)e3 * 64 + lane]);
        a0.x += v0.x; a0.y += v0.y;
        a1.x += v1.x; a1.y += v1.y;
        a2.x += v2.x; a2.y += v2.y;
        a3.x += v3.x; a3.y += v3.y;
    }
    for (; p < pe; ++p) {
        int e0 = csr_src[p];
        float2 v0 = __half22float2(hw16[(size_t)e0 * 64 + lane]);
        a0.x += v0.x; a0.y += v0.y;
    }

    float sx = (a0.x + a1.x) + (a2.x + a3.x);
    float sy = (a0.y + a1.y) + (a2.y + a3.y);
    float d = dinv[node];
    float2 b = *(const float2*)(bias + lane * 2);
    float2 o;
    o.x = fmaxf(fmaf(sx, d, b.x), 0.f);
    o.y = fmaxf(fmaf(sy, d, b.y), 0.f);
    *(float2*)(out + (size_t)node * FD + lane * 2) = o;
}

// ---------------- mean pool: register run-accumulate + LDS slots + few global atomics ----------------
__global__ __launch_bounds__(256) void k_pool(const float* __restrict__ h,
                                              const int* __restrict__ batch,
                                              float* __restrict__ pool,
                                              int* __restrict__ cnt) {
    __shared__ float lacc[8][128];
    __shared__ int   lcnt[8];
    int t  = threadIdx.x;
    int f4 = t & 31;
    int r  = t >> 5;
    int base = blockIdx.x * 256;

    for (int i = t; i < 8 * 128; i += 256) ((float*)lacc)[i] = 0.f;
    if (t < 8) lcnt[t] = 0;
    __syncthreads();

    int g0 = batch[base];
    int lastnode = base + 255; if (lastnode >= NN) lastnode = NN - 1;
    int span = batch[lastnode] - g0 + 1;

    float4 acc = make_float4(0.f, 0.f, 0.f, 0.f);
    int curg = -1, ccount = 0;
    for (int k = 0; k < 32; ++k) {
        int node = base + (k << 3) + r;
        if (node >= NN) break;
        int g = batch[node];
        float4 v = ((const float4*)h)[(size_t)node * 32 + f4];
        if (g != curg) {
            if (curg >= 0) {
                int s = curg - g0;
                if (s < 8) {
                    atomicAdd(&lacc[s][f4 * 4 + 0], acc.x);
                    atomicAdd(&lacc[s][f4 * 4 + 1], acc.y);
                    atomicAdd(&lacc[s][f4 * 4 + 2], acc.z);
                    atomicAdd(&lacc[s][f4 * 4 + 3], acc.w);
                    if (f4 == 0) atomicAdd(&lcnt[s], ccount);
                } else {
                    float* dst = pool + (size_t)curg * FD + f4 * 4;
                    unsafeAtomicAdd(dst + 0, acc.x);
                    unsafeAtomicAdd(dst + 1, acc.y);
                    unsafeAtomicAdd(dst + 2, acc.z);
                    unsafeAtomicAdd(dst + 3, acc.w);
                    if (f4 == 0) atomicAdd(&cnt[curg], ccount);
                }
            }
            curg = g; acc = make_float4(0.f, 0.f, 0.f, 0.f); ccount = 0;
        }
        acc.x += v.x; acc.y += v.y; acc.z += v.z; acc.w += v.w;
        ccount++;
    }
    if (curg >= 0) {
        int s = curg - g0;
        if (s < 8) {
            atomicAdd(&lacc[s][f4 * 4 + 0], acc.x);
            atomicAdd(&lacc[s][f4 * 4 + 1], acc.y);
            atomicAdd(&lacc[s][f4 * 4 + 2], acc.z);
            atomicAdd(&lacc[s][f4 * 4 + 3], acc.w);
            if (f4 == 0) atomicAdd(&lcnt[s], ccount);
        } else {
            float* dst = pool + (size_t)curg * FD + f4 * 4;
            unsafeAtomicAdd(dst + 0, acc.x);
            unsafeAtomicAdd(dst + 1, acc.y);
            unsafeAtomicAdd(dst + 2, acc.z);
            unsafeAtomicAdd(dst + 3, acc.w);
            if (f4 == 0) atomicAdd(&cnt[curg], ccount);
        }
    }
    __syncthreads();
    if (span > 8) span = 8;
    for (int s = 0; s < span; ++s) {
        for (int i = t; i < 128; i += 256)
            unsafeAtomicAdd(&pool[(size_t)(g0 + s) * FD + i], lacc[s][i]);
        if (t == 0 && lcnt[s]) atomicAdd(&cnt[g0 + s], lcnt[s]);
    }
}

// ---------------- MLP head ----------------
__global__ __launch_bounds__(128) void k_mlp(const float* __restrict__ pool,
                                             const int* __restrict__ cnt,
                                             const float* __restrict__ W1,
                                             const float* __restrict__ b1,
                                             const float* __restrict__ W2,
                                             const float* __restrict__ b2,
                                             float* __restrict__ out) {
    int g = blockIdx.x, j = threadIdx.x;
    __shared__ float gm[FD];
    float c = fmaxf((float)cnt[g], 1.0f);
    gm[j] = pool[(size_t)g * FD + j] / c;
    __syncthreads();
    float v = b1[j];
#pragma unroll 8
    for (int k = 0; k < FD; ++k) v = fmaf(gm[k], W1[(size_t)k * FD + j], v);
    v = fmaxf(v, 0.f);
    float p = v * W2[j];
#pragma unroll
    for (int off = 32; off; off >>= 1) p += __shfl_down(p, off);
    __shared__ float part[2];
    if ((j & 63) == 0) part[j >> 6] = p;
    __syncthreads();
    if (j == 0) out[g] = part[0] + part[1] + b2[0];
}

extern "C" void kernel_launch(void* const* d_in, const int* in_sizes, int n_in,
                              void* d_out, int out_size, void* d_ws, size_t ws_size,
                              hipStream_t stream) {
    const float* x     = (const float*)d_in[0];
    const int*   ei    = (const int*)d_in[1];    // [2][NE]
    const int*   batch = (const int*)d_in[2];
    const float* convW = (const float*)d_in[3];
    const float* convB = (const float*)d_in[4];
    const float* linW1 = (const float*)d_in[5];
    const float* linB1 = (const float*)d_in[6];
    const float* linW2 = (const float*)d_in[7];
    const float* linB2 = (const float*)d_in[8];
    float* out = (float*)d_out;

    char* ws = (char*)d_ws;
    // layout: ints/csr in first 9MB, hw16 (half, 25.6MB) @9MB, hbuf (f32, 51.2MB) @36MB, pool @90MB
    int*   degi    = (int*)ws;                                   // NN ints
    float* dinv    = (float*)(ws + 400 * 1024);
    int*   start   = (int*)(ws + 800 * 1024);                    // NN ints
    int*   cursor  = (int*)(ws + 1200 * 1024);                   // NN ints
    int*   partial = (int*)(ws + 1600 * 1024);                   // 512 ints
    int*   csr_src = (int*)(ws + ((size_t)2 << 20));             // NE ints (6.4MB)
    __half* hw16   = (__half*)(ws + ((size_t)9 << 20));          // NN*FD half (25.6MB)
    float* hbuf    = (float*)(ws + ((size_t)36 << 20));          // NN*FD f32 (51.2MB)
    float* pool    = (float*)(ws + ((size_t)90 << 20));          // NG*FD
    int*   cnt     = (int*)(pool + NG * FD);

    const int* row = ei;        // sources
    const int* col = ei + NE;   // targets

    // CSR build + norms
    hipMemsetAsync(degi, 0, NN * sizeof(int), stream);
    k_hist<<<(NE + 255) / 256, 256, 0, stream>>>(col, degi);
    k_dinv<<<(NN + 255) / 256, 256, 0, stream>>>(degi, dinv);
    k_scanA<<<NB_SCAN, 256, 0, stream>>>(degi, partial);
    k_scanB<<<1, 512, 0, stream>>>(partial);
    k_scanC<<<NB_SCAN, 256, 0, stream>>>(degi, partial, start, cursor);
    k_fill<<<(NE + 255) / 256, 256, 0, stream>>>(row, col, cursor, csr_src);

    const float* h = x;
    for (int l = 0; l < NL; ++l) {
        k_gemm<<<(NN + 127) / 128, 256, 0, stream>>>(h, convW + (size_t)l * FD * FD, dinv, hw16, NN);
        k_gather<<<(NN + 3) / 4, 256, 0, stream>>>((const __half2*)hw16, start, csr_src, dinv,
                                                   convB + (size_t)l * FD, hbuf);
        h = hbuf;
    }

    hipMemsetAsync(pool, 0, (size_t)(NG * FD) * sizeof(float) + NG * sizeof(int), stream);
    k_pool<<<(NN + 255) / 256, 256, 0, stream>>>(h, batch, pool, cnt);
    k_mlp<<<NG, 128, 0, stream>>>(pool, cnt, linW1, linB1, linW2, linB2, out);
}

// Round 8
// 646.299 us; speedup vs baseline: 14.5368x; 1.0578x over previous
//
#include <hip/hip_runtime.h>
#include <hip/hip_bf16.h>
#include <hip/hip_fp16.h>

#define NN 100000
#define NE 1600000
#define FD 128
#define NG 64
#define NL 3
#define NB_SCAN 391   // ceil(NN/256)

typedef _Float16 half8 __attribute__((ext_vector_type(8)));
typedef float    f32x4 __attribute__((ext_vector_type(4)));

// ---------------- CSR build: histogram ----------------
__global__ __launch_bounds__(256) void k_hist(const int* __restrict__ col, int* __restrict__ degi) {
    int e = blockIdx.x * 256 + threadIdx.x;
    if (e < NE) atomicAdd(&degi[col[e]], 1);
}

// dinv[i] = 1/sqrt(deg_i + 1)  (self-loop included)
__global__ __launch_bounds__(256) void k_dinv(const int* __restrict__ degi, float* __restrict__ dinv) {
    int i = blockIdx.x * 256 + threadIdx.x;
    if (i < NN) dinv[i] = 1.0f / sqrtf((float)(degi[i] + 1));
}

// ---------------- 3-pass exclusive scan of degi -> start/cursor ----------------
__global__ __launch_bounds__(256) void k_scanA(const int* __restrict__ degi, int* __restrict__ partial) {
    __shared__ int sd[256];
    int t = threadIdx.x;
    int i = blockIdx.x * 256 + t;
    sd[t] = (i < NN) ? degi[i] : 0;
    __syncthreads();
#pragma unroll
    for (int off = 128; off; off >>= 1) {
        if (t < off) sd[t] += sd[t + off];
        __syncthreads();
    }
    if (t == 0) partial[blockIdx.x] = sd[0];
}

__global__ __launch_bounds__(512) void k_scanB(int* __restrict__ partial) {
    __shared__ int sd[512];
    int t = threadIdx.x;
    int v = (t < NB_SCAN) ? partial[t] : 0;
    sd[t] = v;
    __syncthreads();
    for (int off = 1; off < 512; off <<= 1) {
        int x = (t >= off) ? sd[t - off] : 0;
        __syncthreads();
        sd[t] += x;
        __syncthreads();
    }
    if (t < NB_SCAN) partial[t] = sd[t] - v;   // exclusive
}

__global__ __launch_bounds__(256) void k_scanC(const int* __restrict__ degi,
                                               const int* __restrict__ blockoff,
                                               int* __restrict__ start, int* __restrict__ cursor) {
    __shared__ int sd[256];
    int t = threadIdx.x;
    int i = blockIdx.x * 256 + t;
    int v = (i < NN) ? degi[i] : 0;
    sd[t] = v;
    __syncthreads();
    for (int off = 1; off < 256; off <<= 1) {
        int x = (t >= off) ? sd[t - off] : 0;
        __syncthreads();
        sd[t] += x;
        __syncthreads();
    }
    int ex = sd[t] - v + blockoff[blockIdx.x];
    if (i < NN) { start[i] = ex; cursor[i] = ex; }
}

__global__ __launch_bounds__(256) void k_fill(const int* __restrict__ row, const int* __restrict__ col,
                                              int* __restrict__ cursor, int* __restrict__ csr_src) {
    int e = blockIdx.x * 256 + threadIdx.x;
    if (e < NE) {
        int c = col[e];
        int p = atomicAdd(&cursor[c], 1);
        csr_src[p] = row[e];
    }
}

// ---------------- cast x (f32) -> fp16 ----------------
__global__ __launch_bounds__(256) void k_cast(const float* __restrict__ x, __half* __restrict__ x16) {
    int i = blockIdx.x * 256 + threadIdx.x;   // over NN*32 float4 groups
    if (i >= NN * 32) return;
    float4 v = ((const float4*)x)[i];
    __half2 h0 = __float22half2_rn(make_float2(v.x, v.y));
    __half2 h1 = __float22half2_rn(make_float2(v.z, v.w));
    ((__half2*)x16)[i * 2 + 0] = h0;
    ((__half2*)x16)[i * 2 + 1] = h1;
}

// ---------------- transpose+cast W: Wt[l][n][k] = half(W[l][k][n]) ----------------
__global__ __launch_bounds__(256) void k_wprep(const float* __restrict__ W, __half* __restrict__ Wt) {
    int idx = blockIdx.x * 256 + threadIdx.x;   // 3*128*128
    if (idx >= NL * FD * FD) return;
    int l  = idx >> 14;
    int r  = idx & 16383;
    int nn = r >> 7;
    int kk = r & 127;
    Wt[(size_t)l * FD * FD + nn * FD + kk] = __float2half(W[(size_t)l * FD * FD + kk * FD + nn]);
}

// ---------------- MFMA GEMM: C16[n][128] = half((A16[n][128] @ W) * dinv[n]) ----------------
// 256 thr = 4 waves; wave computes 16 rows x 128 cols via 8 col-tiles of 16x16x32 f16 MFMA.
// B from Wt (N x K layout) so both fragments are contiguous 16B loads. No LDS.
__global__ __launch_bounds__(256) void k_gemm(const __half* __restrict__ A16,
                                              const __half* __restrict__ Wt,
                                              const float* __restrict__ dinv,
                                              __half* __restrict__ C16, int n) {
    int wid  = threadIdx.x >> 6;
    int lane = threadIdx.x & 63;
    int row0 = blockIdx.x * 64 + wid * 16;
    int lr   = lane & 15;    // A row / B col / C col within tile
    int kg   = lane >> 4;    // k-group (8 halves each)

    f32x4 acc[8];
#pragma unroll
    for (int t = 0; t < 8; ++t) acc[t] = (f32x4){0.f, 0.f, 0.f, 0.f};

    int arow = row0 + lr;
#pragma unroll
    for (int kc = 0; kc < 4; ++kc) {
        half8 a = (half8)(0);
        if (arow < n)
            a = *(const half8*)(A16 + (size_t)arow * FD + kc * 32 + kg * 8);
#pragma unroll
        for (int t = 0; t < 8; ++t) {
            half8 b = *(const half8*)(Wt + (size_t)(t * 16 + lr) * FD + kc * 32 + kg * 8);
            acc[t] = __builtin_amdgcn_mfma_f32_16x16x32_f16(a, b, acc[t], 0, 0, 0);
        }
    }

    // C/D: col = lane&15, row = (lane>>4)*4 + q   [m89 verified mapping]
    float dv[4];
    int   rr[4];
#pragma unroll
    for (int q = 0; q < 4; ++q) {
        rr[q] = row0 + kg * 4 + q;
        dv[q] = (rr[q] < n) ? dinv[rr[q]] : 0.f;
    }
#pragma unroll
    for (int t = 0; t < 8; ++t) {
#pragma unroll
        for (int q = 0; q < 4; ++q) {
            if (rr[q] < n)
                C16[(size_t)rr[q] * FD + t * 16 + lr] = __float2half(acc[t][q] * dv[q]);
        }
    }
}

// ---------------- gather-aggregate: h16[c] = half(relu(dinv[c]*(hw'[c] + sum_in hw'[src]) + b)) ----------------
// one wave per node, half2 per lane, wave-uniform scalar CSR index loads, 8-way ILP unroll.
__global__ __launch_bounds__(256) void k_gather(const __half2* __restrict__ hw16,
                                                const int* __restrict__ start,
                                                const int* __restrict__ csr_src,
                                                const float* __restrict__ dinv,
                                                const float* __restrict__ bias,
                                                __half2* __restrict__ outh) {
    int node = blockIdx.x * 4 + (threadIdx.x >> 6);
    if (node >= NN) return;
    int lane = threadIdx.x & 63;

    int p  = __builtin_amdgcn_readfirstlane(start[node]);
    int pe = __builtin_amdgcn_readfirstlane((node < NN - 1) ? start[node + 1] : NE);

    float2 a0 = __half22float2(hw16[(size_t)node * 64 + lane]);  // self term
    float2 a1 = make_float2(0.f, 0.f);
    float2 a2 = make_float2(0.f, 0.f);
    float2 a3 = make_float2(0.f, 0.f);

    for (; p + 8 <= pe; p += 8) {
        int e0 = csr_src[p + 0];
        int e1 = csr_src[p + 1];
        int e2 = csr_src[p + 2];
        int e3 = csr_src[p + 3];
        int e4 = csr_src[p + 4];
        int e5 = csr_src[p + 5];
        int e6 = csr_src[p + 6];
        int e7 = csr_src[p + 7];
        float2 v0 = __half22float2(hw16[(size_t)e0 * 64 + lane]);
        float2 v1 = __half22float2(hw16[(size_t)e1 * 64 + lane]);
        float2 v2 = __half22float2(hw16[(size_t)e2 * 64 + lane]);
        float2 v3 = __half22float2(hw16[(size_t)e3 * 64 + lane]);
        float2 v4 = __half22float2(hw16[(size_t)e4 * 64 + lane]);
        float2 v5 = __half22float2(hw16[(size_t)e5 * 64 + lane]);
        float2 v6 = __half22float2(hw16[(size_t)e6 * 64 + lane]);
        float2 v7 = __half22float2(hw16[(size_t)e7 * 64 + lane]);
        a0.x += v0.x; a0.y += v0.y;  a1.x += v1.x; a1.y += v1.y;
        a2.x += v2.x; a2.y += v2.y;  a3.x += v3.x; a3.y += v3.y;
        a0.x += v4.x; a0.y += v4.y;  a1.x += v5.x; a1.y += v5.y;
        a2.x += v6.x; a2.y += v6.y;  a3.x += v7.x; a3.y += v7.y;
    }
    for (; p < pe; ++p) {
        int e0 = csr_src[p];
        float2 v0 = __half22float2(hw16[(size_t)e0 * 64 + lane]);
        a0.x += v0.x; a0.y += v0.y;
    }

    float sx = (a0.x + a1.x) + (a2.x + a3.x);
    float sy = (a0.y + a1.y) + (a2.y + a3.y);
    float d = dinv[node];
    float2 b = *(const float2*)(bias + lane * 2);
    float ox = fmaxf(fmaf(sx, d, b.x), 0.f);
    float oy = fmaxf(fmaf(sy, d, b.y), 0.f);
    outh[(size_t)node * 64 + lane] = __float22half2_rn(make_float2(ox, oy));
}

// ---------------- mean pool (reads fp16 h): register run-accumulate + LDS slots ----------------
__global__ __launch_bounds__(256) void k_pool(const __half2* __restrict__ h,
                                              const int* __restrict__ batch,
                                              float* __restrict__ pool,
                                              int* __restrict__ cnt) {
    __shared__ float lacc[8][128];
    __shared__ int   lcnt[8];
    int t  = threadIdx.x;
    int f4 = t & 31;
    int r  = t >> 5;
    int base = blockIdx.x * 256;

    for (int i = t; i < 8 * 128; i += 256) ((float*)lacc)[i] = 0.f;
    if (t < 8) lcnt[t] = 0;
    __syncthreads();

    int g0 = batch[base];
    int lastnode = base + 255; if (lastnode >= NN) lastnode = NN - 1;
    int span = batch[lastnode] - g0 + 1;

    float4 acc = make_float4(0.f, 0.f, 0.f, 0.f);
    int curg = -1, ccount = 0;
    for (int k = 0; k < 32; ++k) {
        int node = base + (k << 3) + r;
        if (node >= NN) break;
        int g = batch[node];
        float2 f0 = __half22float2(h[(size_t)node * 64 + f4 * 2 + 0]);
        float2 f1 = __half22float2(h[(size_t)node * 64 + f4 * 2 + 1]);
        float4 v = make_float4(f0.x, f0.y, f1.x, f1.y);
        if (g != curg) {
            if (curg >= 0) {
                int s = curg - g0;
                if (s < 8) {
                    atomicAdd(&lacc[s][f4 * 4 + 0], acc.x);
                    atomicAdd(&lacc[s][f4 * 4 + 1], acc.y);
                    atomicAdd(&lacc[s][f4 * 4 + 2], acc.z);
                    atomicAdd(&lacc[s][f4 * 4 + 3], acc.w);
                    if (f4 == 0) atomicAdd(&lcnt[s], ccount);
                } else {
                    float* dst = pool + (size_t)curg * FD + f4 * 4;
                    unsafeAtomicAdd(dst + 0, acc.x);
                    unsafeAtomicAdd(dst + 1, acc.y);
                    unsafeAtomicAdd(dst + 2, acc.z);
                    unsafeAtomicAdd(dst + 3, acc.w);
                    if (f4 == 0) atomicAdd(&cnt[curg], ccount);
                }
            }
            curg = g; acc = make_float4(0.f, 0.f, 0.f, 0.f); ccount = 0;
        }
        acc.x += v.x; acc.y += v.y; acc.z += v.z; acc.w += v.w;
        ccount++;
    }
    if (curg >= 0) {
        int s = curg - g0;
        if (s < 8) {
            atomicAdd(&lacc[s][f4 * 4 + 0], acc.x);
            atomicAdd(&lacc[s][f4 * 4 + 1], acc.y);
            atomicAdd(&lacc[s][f4 * 4 + 2], acc.z);
            atomicAdd(&lacc[s][f4 * 4 + 3], acc.w);
            if (f4 == 0) atomicAdd(&lcnt[s], ccount);
        } else {
            float* dst = pool + (size_t)curg * FD + f4 * 4;
            unsafeAtomicAdd(dst + 0, acc.x);
            unsafeAtomicAdd(dst + 1, acc.y);
            unsafeAtomicAdd(dst + 2, acc.z);
            unsafeAtomicAdd(dst + 3, acc.w);
            if (f4 == 0) atomicAdd(&cnt[curg], ccount);
        }
    }
    __syncthreads();
    if (span > 8) span = 8;
    for (int s = 0; s < span; ++s) {
        for (int i = t; i < 128; i += 256)
            unsafeAtomicAdd(&pool[(size_t)(g0 + s) * FD + i], lacc[s][i]);
        if (t == 0 && lcnt[s]) atomicAdd(&cnt[g0 + s], lcnt[s]);
    }
}

// ---------------- MLP head ----------------
__global__ __launch_bounds__(128) void k_mlp(const float* __restrict__ pool,
                                             const int* __restrict__ cnt,
                                             const float* __restrict__ W1,
                                             const float* __restrict__ b1,
                                             const float* __restrict__ W2,
                                             const float* __restrict__ b2,
                                             float* __restrict__ out) {
    int g = blockIdx.x, j = threadIdx.x;
    __shared__ float gm[FD];
    float c = fmaxf((float)cnt[g], 1.0f);
    gm[j] = pool[(size_t)g * FD + j] / c;
    __syncthreads();
    float v = b1[j];
#pragma unroll 8
    for (int k = 0; k < FD; ++k) v = fmaf(gm[k], W1[(size_t)k * FD + j], v);
    v = fmaxf(v, 0.f);
    float p = v * W2[j];
#pragma unroll
    for (int off = 32; off; off >>= 1) p += __shfl_down(p, off);
    __shared__ float part[2];
    if ((j & 63) == 0) part[j >> 6] = p;
    __syncthreads();
    if (j == 0) out[g] = part[0] + part[1] + b2[0];
}

extern "C" void kernel_launch(void* const* d_in, const int* in_sizes, int n_in,
                              void* d_out, int out_size, void* d_ws, size_t ws_size,
                              hipStream_t stream) {
    const float* x     = (const float*)d_in[0];
    const int*   ei    = (const int*)d_in[1];    // [2][NE]
    const int*   batch = (const int*)d_in[2];
    const float* convW = (const float*)d_in[3];
    const float* convB = (const float*)d_in[4];
    const float* linW1 = (const float*)d_in[5];
    const float* linB1 = (const float*)d_in[6];
    const float* linW2 = (const float*)d_in[7];
    const float* linB2 = (const float*)d_in[8];
    float* out = (float*)d_out;

    char* ws = (char*)d_ws;
    int*    degi    = (int*)ws;                                   // NN ints
    float*  dinv    = (float*)(ws + 400 * 1024);
    int*    start   = (int*)(ws + 800 * 1024);
    int*    cursor  = (int*)(ws + 1200 * 1024);
    int*    partial = (int*)(ws + 1600 * 1024);
    int*    csr_src = (int*)(ws + ((size_t)2 << 20));             // 6.4MB
    __half* Wt16    = (__half*)(ws + ((size_t)9 << 20));          // 3*128*128 half (96KB)
    __half* bufA    = (__half*)(ws + ((size_t)10 << 20));         // NN*FD half (25.6MB) - h input
    __half* bufB    = (__half*)(ws + ((size_t)36 << 20));         // NN*FD half (25.6MB) - hw'
    float*  pool    = (float*)(ws + ((size_t)62 << 20));          // NG*FD
    int*    cnt     = (int*)(pool + NG * FD);

    const int* row = ei;        // sources
    const int* col = ei + NE;   // targets

    // CSR build + norms + fp16 prep
    hipMemsetAsync(degi, 0, NN * sizeof(int), stream);
    k_hist<<<(NE + 255) / 256, 256, 0, stream>>>(col, degi);
    k_dinv<<<(NN + 255) / 256, 256, 0, stream>>>(degi, dinv);
    k_scanA<<<NB_SCAN, 256, 0, stream>>>(degi, partial);
    k_scanB<<<1, 512, 0, stream>>>(partial);
    k_scanC<<<NB_SCAN, 256, 0, stream>>>(degi, partial, start, cursor);
    k_fill<<<(NE + 255) / 256, 256, 0, stream>>>(row, col, cursor, csr_src);
    k_cast<<<(NN * 32 + 255) / 256, 256, 0, stream>>>(x, bufA);
    k_wprep<<<(NL * FD * FD + 255) / 256, 256, 0, stream>>>(convW, Wt16);

    for (int l = 0; l < NL; ++l) {
        k_gemm<<<(NN + 63) / 64, 256, 0, stream>>>(bufA, Wt16 + (size_t)l * FD * FD, dinv, bufB, NN);
        k_gather<<<(NN + 3) / 4, 256, 0, stream>>>((const __half2*)bufB, start, csr_src, dinv,
                                                   convB + (size_t)l * FD, (__half2*)bufA);
    }

    hipMemsetAsync(pool, 0, (size_t)(NG * FD) * sizeof(float) + NG * sizeof(int), stream);
    k_pool<<<(NN + 255) / 256, 256, 0, stream>>>((const __half2*)bufA, batch, pool, cnt);
    k_mlp<<<NG, 128, 0, stream>>>(pool, cnt, linW1, linB1, linW2, linB2, out);
}

// Round 14
// 521.979 us; speedup vs baseline: 17.9990x; 1.2382x over previous
//
#include <hip/hip_runtime.h>
#include <hip/hip_bf16.h>
#include <hip/hip_fp16.h>

#define NN 100000
#define NE 1600000
#define FD 128
#define NG 64
#define NL 3
#define NBK 391      // buckets of 256 nodes: ceil(100000/256)
#define BSH 8        // node >> 8 = bucket

typedef _Float16 half8 __attribute__((ext_vector_type(8)));
typedef float    f32x4 __attribute__((ext_vector_type(4)));

// ---------------- bucket histogram (LDS-combined) ----------------
__global__ __launch_bounds__(256) void k_bhist(const int* __restrict__ col, int* __restrict__ bucketDeg) {
    __shared__ int cnt[NBK];
    int t = threadIdx.x;
    for (int i = t; i < NBK; i += 256) cnt[i] = 0;
    __syncthreads();
    int base = blockIdx.x * 4096;
    for (int i = t; i < 4096; i += 256) {
        int e = base + i;
        if (e < NE) atomicAdd(&cnt[col[e] >> BSH], 1);
    }
    __syncthreads();
    for (int i = t; i < NBK; i += 256)
        if (cnt[i]) atomicAdd(&bucketDeg[i], cnt[i]);
}

// ---------------- bucket exclusive scan ----------------
__global__ __launch_bounds__(512) void k_bscan(const int* __restrict__ bucketDeg,
                                               int* __restrict__ bucketBase,
                                               int* __restrict__ bucketCursor) {
    __shared__ int sd[512];
    int t = threadIdx.x;
    int v = (t < NBK) ? bucketDeg[t] : 0;
    sd[t] = v;
    __syncthreads();
    for (int off = 1; off < 512; off <<= 1) {
        int x = (t >= off) ? sd[t - off] : 0;
        __syncthreads();
        sd[t] += x;
        __syncthreads();
    }
    if (t < NBK) { int ex = sd[t] - v; bucketBase[t] = ex; bucketCursor[t] = ex; }
    if (t == 0) bucketBase[NBK] = NE;
}

// ---------------- bin edges into per-bucket contiguous lists ----------------
__global__ __launch_bounds__(256) void k_bin(const int* __restrict__ row, const int* __restrict__ col,
                                             int* __restrict__ bucketCursor, int2* __restrict__ blist) {
    __shared__ int cnt[NBK];
    __shared__ int cnt2[NBK];
    __shared__ int cbase[NBK];
    int t = threadIdx.x;
    for (int i = t; i < NBK; i += 256) { cnt[i] = 0; cnt2[i] = 0; }
    __syncthreads();
    int base = blockIdx.x * 4096;
    for (int i = t; i < 4096; i += 256) {
        int e = base + i;
        if (e < NE) atomicAdd(&cnt[col[e] >> BSH], 1);
    }
    __syncthreads();
    for (int i = t; i < NBK; i += 256)
        cbase[i] = cnt[i] ? atomicAdd(&bucketCursor[i], cnt[i]) : 0;
    __syncthreads();
    for (int i = t; i < 4096; i += 256) {
        int e = base + i;
        if (e < NE) {
            int c = col[e];
            int b = c >> BSH;
            int p = cbase[b] + atomicAdd(&cnt2[b], 1);
            blist[p] = make_int2(row[e], c);
        }
    }
}

// ---------------- per-bucket: node degrees + start[] + dinv[] + csr fill (all L2/LDS-local) ----------------
__global__ __launch_bounds__(256) void k_fill2(const int2* __restrict__ blist,
                                               const int* __restrict__ bucketBase,
                                               int* __restrict__ start,
                                               float* __restrict__ dinv,
                                               int* __restrict__ csr_src) {
    __shared__ int dcnt[256];
    __shared__ int sscan[256];
    __shared__ int cur[256];
    int b = blockIdx.x;
    int t = threadIdx.x;
    int n0 = b << BSH;
    int e0 = bucketBase[b], e1 = bucketBase[b + 1];

    dcnt[t] = 0;
    __syncthreads();
    for (int i = e0 + t; i < e1; i += 256)
        atomicAdd(&dcnt[blist[i].y - n0], 1);
    __syncthreads();
    int v = dcnt[t];
    sscan[t] = v;
    __syncthreads();
    for (int off = 1; off < 256; off <<= 1) {
        int x = (t >= off) ? sscan[t - off] : 0;
        __syncthreads();
        sscan[t] += x;
        __syncthreads();
    }
    int st = e0 + (sscan[t] - v);
    int node = n0 + t;
    if (node < NN) {
        start[node] = st;
        dinv[node] = 1.0f / sqrtf((float)(v + 1));
    }
    cur[t] = st;
    __syncthreads();
    for (int i = e0 + t; i < e1; i += 256) {
        int2 e = blist[i];
        int p = atomicAdd(&cur[e.y - n0], 1);
        csr_src[p] = e.x;
    }
}

// ---------------- cast x (f32) -> fp16 ----------------
__global__ __launch_bounds__(256) void k_cast(const float* __restrict__ x, __half* __restrict__ x16) {
    int i = blockIdx.x * 256 + threadIdx.x;   // over NN*32 float4 groups
    if (i >= NN * 32) return;
    float4 v = ((const float4*)x)[i];
    __half2 h0 = __float22half2_rn(make_float2(v.x, v.y));
    __half2 h1 = __float22half2_rn(make_float2(v.z, v.w));
    ((__half2*)x16)[i * 2 + 0] = h0;
    ((__half2*)x16)[i * 2 + 1] = h1;
}

// ---------------- transpose+cast W: Wt[l][n][k] = half(W[l][k][n]) ----------------
__global__ __launch_bounds__(256) void k_wprep(const float* __restrict__ W, __half* __restrict__ Wt) {
    int idx = blockIdx.x * 256 + threadIdx.x;   // 3*128*128
    if (idx >= NL * FD * FD) return;
    int l  = idx >> 14;
    int r  = idx & 16383;
    int nn = r >> 7;
    int kk = r & 127;
    Wt[(size_t)l * FD * FD + nn * FD + kk] = __float2half(W[(size_t)l * FD * FD + kk * FD + nn]);
}

// ---------------- MFMA GEMM: C16[n][128] = half((A16[n][128] @ W) * dinv[n]) ----------------
__global__ __launch_bounds__(256) void k_gemm(const __half* __restrict__ A16,
                                              const __half* __restrict__ Wt,
                                              const float* __restrict__ dinv,
                                              __half* __restrict__ C16, int n) {
    int wid  = threadIdx.x >> 6;
    int lane = threadIdx.x & 63;
    int row0 = blockIdx.x * 64 + wid * 16;
    int lr   = lane & 15;    // A row / B col / C col within tile
    int kg   = lane >> 4;    // k-group (8 halves each)

    f32x4 acc[8];
#pragma unroll
    for (int t = 0; t < 8; ++t) acc[t] = (f32x4){0.f, 0.f, 0.f, 0.f};

    int arow = row0 + lr;
#pragma unroll
    for (int kc = 0; kc < 4; ++kc) {
        half8 a = (half8)(0);
        if (arow < n)
            a = *(const half8*)(A16 + (size_t)arow * FD + kc * 32 + kg * 8);
#pragma unroll
        for (int t = 0; t < 8; ++t) {
            half8 b = *(const half8*)(Wt + (size_t)(t * 16 + lr) * FD + kc * 32 + kg * 8);
            acc[t] = __builtin_amdgcn_mfma_f32_16x16x32_f16(a, b, acc[t], 0, 0, 0);
        }
    }

    // C/D: col = lane&15, row = (lane>>4)*4 + q
    float dv[4];
    int   rr[4];
#pragma unroll
    for (int q = 0; q < 4; ++q) {
        rr[q] = row0 + kg * 4 + q;
        dv[q] = (rr[q] < n) ? dinv[rr[q]] : 0.f;
    }
#pragma unroll
    for (int t = 0; t < 8; ++t) {
#pragma unroll
        for (int q = 0; q < 4; ++q) {
            if (rr[q] < n)
                C16[(size_t)rr[q] * FD + t * 16 + lr] = __float2half(acc[t][q] * dv[q]);
        }
    }
}

// ---------------- gather-aggregate: h16[c] = half(relu(dinv[c]*(hw'[c] + sum_in hw'[src]) + b)) ----------------
__global__ __launch_bounds__(256) void k_gather(const __half2* __restrict__ hw16,
                                                const int* __restrict__ start,
                                                const int* __restrict__ csr_src,
                                                const float* __restrict__ dinv,
                                                const float* __restrict__ bias,
                                                __half2* __restrict__ outh) {
    int node = blockIdx.x * 4 + (threadIdx.x >> 6);
    if (node >= NN) return;
    int lane = threadIdx.x & 63;

    int p  = __builtin_amdgcn_readfirstlane(start[node]);
    int pe = __builtin_amdgcn_readfirstlane((node < NN - 1) ? start[node + 1] : NE);

    float2 a0 = __half22float2(hw16[(size_t)node * 64 + lane]);  // self term
    float2 a1 = make_float2(0.f, 0.f);
    float2 a2 = make_float2(0.f, 0.f);
    float2 a3 = make_float2(0.f, 0.f);

    for (; p + 8 <= pe; p += 8) {
        int e0 = csr_src[p + 0];
        int e1 = csr_src[p + 1];
        int e2 = csr_src[p + 2];
        int e3 = csr_src[p + 3];
        int e4 = csr_src[p + 4];
        int e5 = csr_src[p + 5];
        int e6 = csr_src[p + 6];
        int e7 = csr_src[p + 7];
        float2 v0 = __half22float2(hw16[(size_t)e0 * 64 + lane]);
        float2 v1 = __half22float2(hw16[(size_t)e1 * 64 + lane]);
        float2 v2 = __half22float2(hw16[(size_t)e2 * 64 + lane]);
        float2 v3 = __half22float2(hw16[(size_t)e3 * 64 + lane]);
        float2 v4 = __half22float2(hw16[(size_t)e4 * 64 + lane]);
        float2 v5 = __half22float2(hw16[(size_t)e5 * 64 + lane]);
        float2 v6 = __half22float2(hw16[(size_t)e6 * 64 + lane]);
        float2 v7 = __half22float2(hw16[(size_t)e7 * 64 + lane]);
        a0.x += v0.x; a0.y += v0.y;  a1.x += v1.x; a1.y += v1.y;
        a2.x += v2.x; a2.y += v2.y;  a3.x += v3.x; a3.y += v3.y;
        a0.x += v4.x; a0.y += v4.y;  a1.x += v5.x; a1.y += v5.y;
        a2.x += v6.x; a2.y += v6.y;  a3.x += v7.x; a3.y += v7.y;
    }
    for (; p < pe; ++p) {
        int e0 = csr_src[p];
        float2 v0 = __half22float2(hw16[(size_t)e0 * 64 + lane]);
        a0.x += v0.x; a0.y += v0.y;
    }

    float sx = (a0.x + a1.x) + (a2.x + a3.x);
    float sy = (a0.y + a1.y) + (a2.y + a3.y);
    float d = dinv[node];
    float2 b = *(const float2*)(bias + lane * 2);
    float ox = fmaxf(fmaf(sx, d, b.x), 0.f);
    float oy = fmaxf(fmaf(sy, d, b.y), 0.f);
    outh[(size_t)node * 64 + lane] = __float22half2_rn(make_float2(ox, oy));
}

// ---------------- mean pool (reads fp16 h): register run-accumulate + LDS slots ----------------
__global__ __launch_bounds__(256) void k_pool(const __half2* __restrict__ h,
                                              const int* __restrict__ batch,
                                              float* __restrict__ pool,
                                              int* __restrict__ cnt) {
    __shared__ float lacc[8][128];
    __shared__ int   lcnt[8];
    int t  = threadIdx.x;
    int f4 = t & 31;
    int r  = t >> 5;
    int base = blockIdx.x * 256;

    for (int i = t; i < 8 * 128; i += 256) ((float*)lacc)[i] = 0.f;
    if (t < 8) lcnt[t] = 0;
    __syncthreads();

    int g0 = batch[base];
    int lastnode = base + 255; if (lastnode >= NN) lastnode = NN - 1;
    int span = batch[lastnode] - g0 + 1;

    float4 acc = make_float4(0.f, 0.f, 0.f, 0.f);
    int curg = -1, ccount = 0;
    for (int k = 0; k < 32; ++k) {
        int node = base + (k << 3) + r;
        if (node >= NN) break;
        int g = batch[node];
        float2 f0 = __half22float2(h[(size_t)node * 64 + f4 * 2 + 0]);
        float2 f1 = __half22float2(h[(size_t)node * 64 + f4 * 2 + 1]);
        float4 v = make_float4(f0.x, f0.y, f1.x, f1.y);
        if (g != curg) {
            if (curg >= 0) {
                int s = curg - g0;
                if (s < 8) {
                    atomicAdd(&lacc[s][f4 * 4 + 0], acc.x);
                    atomicAdd(&lacc[s][f4 * 4 + 1], acc.y);
                    atomicAdd(&lacc[s][f4 * 4 + 2], acc.z);
                    atomicAdd(&lacc[s][f4 * 4 + 3], acc.w);
                    if (f4 == 0) atomicAdd(&lcnt[s], ccount);
                } else {
                    float* dst = pool + (size_t)curg * FD + f4 * 4;
                    unsafeAtomicAdd(dst + 0, acc.x);
                    unsafeAtomicAdd(dst + 1, acc.y);
                    unsafeAtomicAdd(dst + 2, acc.z);
                    unsafeAtomicAdd(dst + 3, acc.w);
                    if (f4 == 0) atomicAdd(&cnt[curg], ccount);
                }
            }
            curg = g; acc = make_float4(0.f, 0.f, 0.f, 0.f); ccount = 0;
        }
        acc.x += v.x; acc.y += v.y; acc.z += v.z; acc.w += v.w;
        ccount++;
    }
    if (curg >= 0) {
        int s = curg - g0;
        if (s < 8) {
            atomicAdd(&lacc[s][f4 * 4 + 0], acc.x);
            atomicAdd(&lacc[s][f4 * 4 + 1], acc.y);
            atomicAdd(&lacc[s][f4 * 4 + 2], acc.z);
            atomicAdd(&lacc[s][f4 * 4 + 3], acc.w);
            if (f4 == 0) atomicAdd(&lcnt[s], ccount);
        } else {
            float* dst = pool + (size_t)curg * FD + f4 * 4;
            unsafeAtomicAdd(dst + 0, acc.x);
            unsafeAtomicAdd(dst + 1, acc.y);
            unsafeAtomicAdd(dst + 2, acc.z);
            unsafeAtomicAdd(dst + 3, acc.w);
            if (f4 == 0) atomicAdd(&cnt[curg], ccount);
        }
    }
    __syncthreads();
    if (span > 8) span = 8;
    for (int s = 0; s < span; ++s) {
        for (int i = t; i < 128; i += 256)
            unsafeAtomicAdd(&pool[(size_t)(g0 + s) * FD + i], lacc[s][i]);
        if (t == 0 && lcnt[s]) atomicAdd(&cnt[g0 + s], lcnt[s]);
    }
}

// ---------------- MLP head ----------------
__global__ __launch_bounds__(128) void k_mlp(const float* __restrict__ pool,
                                             const int* __restrict__ cnt,
                                             const float* __restrict__ W1,
                                             const float* __restrict__ b1,
                                             const float* __restrict__ W2,
                                             const float* __restrict__ b2,
                                             float* __restrict__ out) {
    int g = blockIdx.x, j = threadIdx.x;
    __shared__ float gm[FD];
    float c = fmaxf((float)cnt[g], 1.0f);
    gm[j] = pool[(size_t)g * FD + j] / c;
    __syncthreads();
    float v = b1[j];
#pragma unroll 8
    for (int k = 0; k < FD; ++k) v = fmaf(gm[k], W1[(size_t)k * FD + j], v);
    v = fmaxf(v, 0.f);
    float p = v * W2[j];
#pragma unroll
    for (int off = 32; off; off >>= 1) p += __shfl_down(p, off);
    __shared__ float part[2];
    if ((j & 63) == 0) part[j >> 6] = p;
    __syncthreads();
    if (j == 0) out[g] = part[0] + part[1] + b2[0];
}

extern "C" void kernel_launch(void* const* d_in, const int* in_sizes, int n_in,
                              void* d_out, int out_size, void* d_ws, size_t ws_size,
                              hipStream_t stream) {
    const float* x     = (const float*)d_in[0];
    const int*   ei    = (const int*)d_in[1];    // [2][NE]
    const int*   batch = (const int*)d_in[2];
    const float* convW = (const float*)d_in[3];
    const float* convB = (const float*)d_in[4];
    const float* linW1 = (const float*)d_in[5];
    const float* linB1 = (const float*)d_in[6];
    const float* linW2 = (const float*)d_in[7];
    const float* linB2 = (const float*)d_in[8];
    float* out = (float*)d_out;

    char* ws = (char*)d_ws;
    int*    start     = (int*)ws;                                 // NN ints (400KB)
    float*  dinv      = (float*)(ws + 400 * 1024);                // NN f32
    int*    bucketDeg = (int*)(ws + 800 * 1024);                  // NBK
    int*    bucketBase= (int*)(ws + 804 * 1024);                  // NBK+1
    int*    bucketCur = (int*)(ws + 808 * 1024);                  // NBK
    int*    csr_src   = (int*)(ws + ((size_t)1 << 20));           // NE ints (6.4MB)
    int2*   blist     = (int2*)(ws + ((size_t)8 << 20));          // NE int2 (12.8MB)
    __half* Wt16      = (__half*)(ws + ((size_t)21 << 20));       // 96KB
    __half* bufA      = (__half*)(ws + ((size_t)22 << 20));       // 25.6MB
    __half* bufB      = (__half*)(ws + ((size_t)48 << 20));       // 25.6MB
    float*  pool      = (float*)(ws + ((size_t)74 << 20));        // NG*FD
    int*    cnt       = (int*)(pool + NG * FD);

    const int* row = ei;        // sources
    const int* col = ei + NE;   // targets

    // CSR build (bucketed, L2-local) + fp16 prep
    hipMemsetAsync(bucketDeg, 0, NBK * sizeof(int), stream);
    k_bhist<<<(NE + 4095) / 4096, 256, 0, stream>>>(col, bucketDeg);
    k_bscan<<<1, 512, 0, stream>>>(bucketDeg, bucketBase, bucketCur);
    k_bin<<<(NE + 4095) / 4096, 256, 0, stream>>>(row, col, bucketCur, blist);
    k_fill2<<<NBK, 256, 0, stream>>>(blist, bucketBase, start, dinv, csr_src);
    k_cast<<<(NN * 32 + 255) / 256, 256, 0, stream>>>(x, bufA);
    k_wprep<<<(NL * FD * FD + 255) / 256, 256, 0, stream>>>(convW, Wt16);

    for (int l = 0; l < NL; ++l) {
        k_gemm<<<(NN + 63) / 64, 256, 0, stream>>>(bufA, Wt16 + (size_t)l * FD * FD, dinv, bufB, NN);
        k_gather<<<(NN + 3) / 4, 256, 0, stream>>>((const __half2*)bufB, start, csr_src, dinv,
                                                   convB + (size_t)l * FD, (__half2*)bufA);
    }

    hipMemsetAsync(pool, 0, (size_t)(NG * FD) * sizeof(float) + NG * sizeof(int), stream);
    k_pool<<<(NN + 255) / 256, 256, 0, stream>>>((const __half2*)bufA, batch, pool, cnt);
    k_mlp<<<NG, 128, 0, stream>>>(pool, cnt, linW1, linB1, linW2, linB2, out);
}

// Round 16
// 511.149 us; speedup vs baseline: 18.3804x; 1.0212x over previous
//
#include <hip/hip_runtime.h>
#include <hip/hip_bf16.h>
#include <hip/hip_fp16.h>

#define NN 100000
#define NE 1600000
#define FD 128
#define NG 64
#define NL 3
#define NBK 391      // buckets of 256 nodes: ceil(100000/256)
#define BSH 8        // node >> 8 = bucket

typedef _Float16 half8 __attribute__((ext_vector_type(8)));
typedef float    f32x4 __attribute__((ext_vector_type(4)));

// ---------------- bucket histogram (LDS-combined) ----------------
__global__ __launch_bounds__(256) void k_bhist(const int* __restrict__ col, int* __restrict__ bucketDeg) {
    __shared__ int cnt[NBK];
    int t = threadIdx.x;
    for (int i = t; i < NBK; i += 256) cnt[i] = 0;
    __syncthreads();
    int base = blockIdx.x * 4096;
    for (int i = t; i < 4096; i += 256) {
        int e = base + i;
        if (e < NE) atomicAdd(&cnt[col[e] >> BSH], 1);
    }
    __syncthreads();
    for (int i = t; i < NBK; i += 256)
        if (cnt[i]) atomicAdd(&bucketDeg[i], cnt[i]);
}

// ---------------- bucket exclusive scan ----------------
__global__ __launch_bounds__(512) void k_bscan(const int* __restrict__ bucketDeg,
                                               int* __restrict__ bucketBase,
                                               int* __restrict__ bucketCursor) {
    __shared__ int sd[512];
    int t = threadIdx.x;
    int v = (t < NBK) ? bucketDeg[t] : 0;
    sd[t] = v;
    __syncthreads();
    for (int off = 1; off < 512; off <<= 1) {
        int x = (t >= off) ? sd[t - off] : 0;
        __syncthreads();
        sd[t] += x;
        __syncthreads();
    }
    if (t < NBK) { int ex = sd[t] - v; bucketBase[t] = ex; bucketCursor[t] = ex; }
    if (t == 0) bucketBase[NBK] = NE;
}

// ---------------- bin edges into per-bucket contiguous lists ----------------
__global__ __launch_bounds__(256) void k_bin(const int* __restrict__ row, const int* __restrict__ col,
                                             int* __restrict__ bucketCursor, int2* __restrict__ blist) {
    __shared__ int cnt[NBK];
    __shared__ int cnt2[NBK];
    __shared__ int cbase[NBK];
    int t = threadIdx.x;
    for (int i = t; i < NBK; i += 256) { cnt[i] = 0; cnt2[i] = 0; }
    __syncthreads();
    int base = blockIdx.x * 4096;
    for (int i = t; i < 4096; i += 256) {
        int e = base + i;
        if (e < NE) atomicAdd(&cnt[col[e] >> BSH], 1);
    }
    __syncthreads();
    for (int i = t; i < NBK; i += 256)
        cbase[i] = cnt[i] ? atomicAdd(&bucketCursor[i], cnt[i]) : 0;
    __syncthreads();
    for (int i = t; i < 4096; i += 256) {
        int e = base + i;
        if (e < NE) {
            int c = col[e];
            int b = c >> BSH;
            int p = cbase[b] + atomicAdd(&cnt2[b], 1);
            blist[p] = make_int2(row[e], c);
        }
    }
}

// ---------------- per-bucket: node degrees + start[] + dinv[] + csr fill (all L2/LDS-local) ----------------
__global__ __launch_bounds__(256) void k_fill2(const int2* __restrict__ blist,
                                               const int* __restrict__ bucketBase,
                                               int* __restrict__ start,
                                               float* __restrict__ dinv,
                                               int* __restrict__ csr_src) {
    __shared__ int dcnt[256];
    __shared__ int sscan[256];
    __shared__ int cur[256];
    int b = blockIdx.x;
    int t = threadIdx.x;
    int n0 = b << BSH;
    int e0 = bucketBase[b], e1 = bucketBase[b + 1];

    dcnt[t] = 0;
    __syncthreads();
    for (int i = e0 + t; i < e1; i += 256)
        atomicAdd(&dcnt[blist[i].y - n0], 1);
    __syncthreads();
    int v = dcnt[t];
    sscan[t] = v;
    __syncthreads();
    for (int off = 1; off < 256; off <<= 1) {
        int x = (t >= off) ? sscan[t - off] : 0;
        __syncthreads();
        sscan[t] += x;
        __syncthreads();
    }
    int st = e0 + (sscan[t] - v);
    int node = n0 + t;
    if (node < NN) {
        start[node] = st;
        dinv[node] = 1.0f / sqrtf((float)(v + 1));
    }
    cur[t] = st;
    __syncthreads();
    for (int i = e0 + t; i < e1; i += 256) {
        int2 e = blist[i];
        int p = atomicAdd(&cur[e.y - n0], 1);
        csr_src[p] = e.x;
    }
}

// ---------------- transpose+cast W: Wt[l][n][k] = half(W[l][k][n]) ----------------
__global__ __launch_bounds__(256) void k_wprep(const float* __restrict__ W, __half* __restrict__ Wt) {
    int idx = blockIdx.x * 256 + threadIdx.x;   // 3*128*128
    if (idx >= NL * FD * FD) return;
    int l  = idx >> 14;
    int r  = idx & 16383;
    int nn = r >> 7;
    int kk = r & 127;
    Wt[(size_t)l * FD * FD + nn * FD + kk] = __float2half(W[(size_t)l * FD * FD + kk * FD + nn]);
}

// ---------------- MFMA GEMM: C16[n][128] = half((A @ W) * dinv[n]) ----------------
// A from fp16 (A16) or f32 (A32, layer 0 — fused cast). Wave-uniform select.
__global__ __launch_bounds__(256) void k_gemm(const __half* __restrict__ A16,
                                              const float* __restrict__ A32,
                                              const __half* __restrict__ Wt,
                                              const float* __restrict__ dinv,
                                              __half* __restrict__ C16, int n) {
    int wid  = threadIdx.x >> 6;
    int lane = threadIdx.x & 63;
    int row0 = blockIdx.x * 64 + wid * 16;
    int lr   = lane & 15;    // A row / B col / C col within tile
    int kg   = lane >> 4;    // k-group (8 halves each)

    f32x4 acc[8];
#pragma unroll
    for (int t = 0; t < 8; ++t) acc[t] = (f32x4){0.f, 0.f, 0.f, 0.f};

    int arow = row0 + lr;
#pragma unroll
    for (int kc = 0; kc < 4; ++kc) {
        half8 a = (half8)(0);
        if (arow < n) {
            if (A32 != nullptr) {
                const float* src = A32 + (size_t)arow * FD + kc * 32 + kg * 8;
                float4 f0 = *(const float4*)(src);
                float4 f1 = *(const float4*)(src + 4);
                a[0] = (_Float16)f0.x; a[1] = (_Float16)f0.y;
                a[2] = (_Float16)f0.z; a[3] = (_Float16)f0.w;
                a[4] = (_Float16)f1.x; a[5] = (_Float16)f1.y;
                a[6] = (_Float16)f1.z; a[7] = (_Float16)f1.w;
            } else {
                a = *(const half8*)(A16 + (size_t)arow * FD + kc * 32 + kg * 8);
            }
        }
#pragma unroll
        for (int t = 0; t < 8; ++t) {
            half8 b = *(const half8*)(Wt + (size_t)(t * 16 + lr) * FD + kc * 32 + kg * 8);
            acc[t] = __builtin_amdgcn_mfma_f32_16x16x32_f16(a, b, acc[t], 0, 0, 0);
        }
    }

    // C/D: col = lane&15, row = (lane>>4)*4 + q
    float dv[4];
    int   rr[4];
#pragma unroll
    for (int q = 0; q < 4; ++q) {
        rr[q] = row0 + kg * 4 + q;
        dv[q] = (rr[q] < n) ? dinv[rr[q]] : 0.f;
    }
#pragma unroll
    for (int t = 0; t < 8; ++t) {
#pragma unroll
        for (int q = 0; q < 4; ++q) {
            if (rr[q] < n)
                C16[(size_t)rr[q] * FD + t * 16 + lr] = __float2half(acc[t][q] * dv[q]);
        }
    }
}

// ---------------- gather-aggregate: h16[c] = half(relu(dinv[c]*(hw'[c] + sum_in hw'[src]) + b)) ----------------
// one wave per node; 16-way ILP unroll (fully-unrolled register arrays), 8-way mid tail, scalar tail.
__global__ __launch_bounds__(256) void k_gather(const __half2* __restrict__ hw16,
                                                const int* __restrict__ start,
                                                const int* __restrict__ csr_src,
                                                const float* __restrict__ dinv,
                                                const float* __restrict__ bias,
                                                __half2* __restrict__ outh) {
    int node = blockIdx.x * 4 + (threadIdx.x >> 6);
    if (node >= NN) return;
    int lane = threadIdx.x & 63;

    int p  = __builtin_amdgcn_readfirstlane(start[node]);
    int pe = __builtin_amdgcn_readfirstlane((node < NN - 1) ? start[node + 1] : NE);

    float2 a0 = __half22float2(hw16[(size_t)node * 64 + lane]);  // self term
    float2 a1 = make_float2(0.f, 0.f);
    float2 a2 = make_float2(0.f, 0.f);
    float2 a3 = make_float2(0.f, 0.f);

    for (; p + 16 <= pe; p += 16) {
        int e[16];
#pragma unroll
        for (int i = 0; i < 16; ++i) e[i] = csr_src[p + i];
        float2 v[16];
#pragma unroll
        for (int i = 0; i < 16; ++i) v[i] = __half22float2(hw16[(size_t)e[i] * 64 + lane]);
#pragma unroll
        for (int i = 0; i < 16; i += 4) {
            a0.x += v[i + 0].x; a0.y += v[i + 0].y;
            a1.x += v[i + 1].x; a1.y += v[i + 1].y;
            a2.x += v[i + 2].x; a2.y += v[i + 2].y;
            a3.x += v[i + 3].x; a3.y += v[i + 3].y;
        }
    }
    for (; p + 8 <= pe; p += 8) {
        int e[8];
#pragma unroll
        for (int i = 0; i < 8; ++i) e[i] = csr_src[p + i];
        float2 v[8];
#pragma unroll
        for (int i = 0; i < 8; ++i) v[i] = __half22float2(hw16[(size_t)e[i] * 64 + lane]);
#pragma unroll
        for (int i = 0; i < 8; i += 4) {
            a0.x += v[i + 0].x; a0.y += v[i + 0].y;
            a1.x += v[i + 1].x; a1.y += v[i + 1].y;
            a2.x += v[i + 2].x; a2.y += v[i + 2].y;
            a3.x += v[i + 3].x; a3.y += v[i + 3].y;
        }
    }
    for (; p < pe; ++p) {
        int e0 = csr_src[p];
        float2 v0 = __half22float2(hw16[(size_t)e0 * 64 + lane]);
        a0.x += v0.x; a0.y += v0.y;
    }

    float sx = (a0.x + a1.x) + (a2.x + a3.x);
    float sy = (a0.y + a1.y) + (a2.y + a3.y);
    float d = dinv[node];
    float2 b = *(const float2*)(bias + lane * 2);
    float ox = fmaxf(fmaf(sx, d, b.x), 0.f);
    float oy = fmaxf(fmaf(sy, d, b.y), 0.f);
    outh[(size_t)node * 64 + lane] = __float22half2_rn(make_float2(ox, oy));
}

// ---------------- mean pool (reads fp16 h): register run-accumulate + LDS slots ----------------
__global__ __launch_bounds__(256) void k_pool(const __half2* __restrict__ h,
                                              const int* __restrict__ batch,
                                              float* __restrict__ pool,
                                              int* __restrict__ cnt) {
    __shared__ float lacc[8][128];
    __shared__ int   lcnt[8];
    int t  = threadIdx.x;
    int f4 = t & 31;
    int r  = t >> 5;
    int base = blockIdx.x * 256;

    for (int i = t; i < 8 * 128; i += 256) ((float*)lacc)[i] = 0.f;
    if (t < 8) lcnt[t] = 0;
    __syncthreads();

    int g0 = batch[base];
    int lastnode = base + 255; if (lastnode >= NN) lastnode = NN - 1;
    int span = batch[lastnode] - g0 + 1;

    float4 acc = make_float4(0.f, 0.f, 0.f, 0.f);
    int curg = -1, ccount = 0;
    for (int k = 0; k < 32; ++k) {
        int node = base + (k << 3) + r;
        if (node >= NN) break;
        int g = batch[node];
        float2 f0 = __half22float2(h[(size_t)node * 64 + f4 * 2 + 0]);
        float2 f1 = __half22float2(h[(size_t)node * 64 + f4 * 2 + 1]);
        float4 v = make_float4(f0.x, f0.y, f1.x, f1.y);
        if (g != curg) {
            if (curg >= 0) {
                int s = curg - g0;
                if (s < 8) {
                    atomicAdd(&lacc[s][f4 * 4 + 0], acc.x);
                    atomicAdd(&lacc[s][f4 * 4 + 1], acc.y);
                    atomicAdd(&lacc[s][f4 * 4 + 2], acc.z);
                    atomicAdd(&lacc[s][f4 * 4 + 3], acc.w);
                    if (f4 == 0) atomicAdd(&lcnt[s], ccount);
                } else {
                    float* dst = pool + (size_t)curg * FD + f4 * 4;
                    unsafeAtomicAdd(dst + 0, acc.x);
                    unsafeAtomicAdd(dst + 1, acc.y);
                    unsafeAtomicAdd(dst + 2, acc.z);
                    unsafeAtomicAdd(dst + 3, acc.w);
                    if (f4 == 0) atomicAdd(&cnt[curg], ccount);
                }
            }
            curg = g; acc = make_float4(0.f, 0.f, 0.f, 0.f); ccount = 0;
        }
        acc.x += v.x; acc.y += v.y; acc.z += v.z; acc.w += v.w;
        ccount++;
    }
    if (curg >= 0) {
        int s = curg - g0;
        if (s < 8) {
            atomicAdd(&lacc[s][f4 * 4 + 0], acc.x);
            atomicAdd(&lacc[s][f4 * 4 + 1], acc.y);
            atomicAdd(&lacc[s][f4 * 4 + 2], acc.z);
            atomicAdd(&lacc[s][f4 * 4 + 3], acc.w);
            if (f4 == 0) atomicAdd(&lcnt[s], ccount);
        } else {
            float* dst = pool + (size_t)curg * FD + f4 * 4;
            unsafeAtomicAdd(dst + 0, acc.x);
            unsafeAtomicAdd(dst + 1, acc.y);
            unsafeAtomicAdd(dst + 2, acc.z);
            unsafeAtomicAdd(dst + 3, acc.w);
            if (f4 == 0) atomicAdd(&cnt[curg], ccount);
        }
    }
    __syncthreads();
    if (span > 8) span = 8;
    for (int s = 0; s < span; ++s) {
        for (int i = t; i < 128; i += 256)
            unsafeAtomicAdd(&pool[(size_t)(g0 + s) * FD + i], lacc[s][i]);
        if (t == 0 && lcnt[s]) atomicAdd(&cnt[g0 + s], lcnt[s]);
    }
}

// ---------------- MLP head ----------------
__global__ __launch_bounds__(128) void k_mlp(const float* __restrict__ pool,
                                             const int* __restrict__ cnt,
                                             const float* __restrict__ W1,
                                             const float* __restrict__ b1,
                                             const float* __restrict__ W2,
                                             const float* __restrict__ b2,
                                             float* __restrict__ out) {
    int g = blockIdx.x, j = threadIdx.x;
    __shared__ float gm[FD];
    float c = fmaxf((float)cnt[g], 1.0f);
    gm[j] = pool[(size_t)g * FD + j] / c;
    __syncthreads();
    float v = b1[j];
#pragma unroll 8
    for (int k = 0; k < FD; ++k) v = fmaf(gm[k], W1[(size_t)k * FD + j], v);
    v = fmaxf(v, 0.f);
    float p = v * W2[j];
#pragma unroll
    for (int off = 32; off; off >>= 1) p += __shfl_down(p, off);
    __shared__ float part[2];
    if ((j & 63) == 0) part[j >> 6] = p;
    __syncthreads();
    if (j == 0) out[g] = part[0] + part[1] + b2[0];
}

extern "C" void kernel_launch(void* const* d_in, const int* in_sizes, int n_in,
                              void* d_out, int out_size, void* d_ws, size_t ws_size,
                              hipStream_t stream) {
    const float* x     = (const float*)d_in[0];
    const int*   ei    = (const int*)d_in[1];    // [2][NE]
    const int*   batch = (const int*)d_in[2];
    const float* convW = (const float*)d_in[3];
    const float* convB = (const float*)d_in[4];
    const float* linW1 = (const float*)d_in[5];
    const float* linB1 = (const float*)d_in[6];
    const float* linW2 = (const float*)d_in[7];
    const float* linB2 = (const float*)d_in[8];
    float* out = (float*)d_out;

    char* ws = (char*)d_ws;
    int*    start     = (int*)ws;                                 // NN ints (400KB)
    float*  dinv      = (float*)(ws + 400 * 1024);                // NN f32
    int*    bucketDeg = (int*)(ws + 800 * 1024);                  // NBK
    int*    bucketBase= (int*)(ws + 804 * 1024);                  // NBK+1
    int*    bucketCur = (int*)(ws + 808 * 1024);                  // NBK
    int*    csr_src   = (int*)(ws + ((size_t)1 << 20));           // NE ints (6.4MB)
    int2*   blist     = (int2*)(ws + ((size_t)8 << 20));          // NE int2 (12.8MB)
    __half* Wt16      = (__half*)(ws + ((size_t)21 << 20));       // 96KB
    __half* bufA      = (__half*)(ws + ((size_t)22 << 20));       // 25.6MB
    __half* bufB      = (__half*)(ws + ((size_t)48 << 20));       // 25.6MB
    float*  pool      = (float*)(ws + ((size_t)74 << 20));        // NG*FD
    int*    cnt       = (int*)(pool + NG * FD);

    const int* row = ei;        // sources
    const int* col = ei + NE;   // targets

    // CSR build (bucketed, L2-local) + fp16 weight prep
    hipMemsetAsync(bucketDeg, 0, NBK * sizeof(int), stream);
    k_bhist<<<(NE + 4095) / 4096, 256, 0, stream>>>(col, bucketDeg);
    k_bscan<<<1, 512, 0, stream>>>(bucketDeg, bucketBase, bucketCur);
    k_bin<<<(NE + 4095) / 4096, 256, 0, stream>>>(row, col, bucketCur, blist);
    k_fill2<<<NBK, 256, 0, stream>>>(blist, bucketBase, start, dinv, csr_src);
    k_wprep<<<(NL * FD * FD + 255) / 256, 256, 0, stream>>>(convW, Wt16);

    for (int l = 0; l < NL; ++l) {
        // layer 0 reads f32 x directly (fused cast); layers 1,2 read fp16 bufA
        k_gemm<<<(NN + 63) / 64, 256, 0, stream>>>(bufA, (l == 0) ? x : nullptr,
                                                   Wt16 + (size_t)l * FD * FD, dinv, bufB, NN);
        k_gather<<<(NN + 3) / 4, 256, 0, stream>>>((const __half2*)bufB, start, csr_src, dinv,
                                                   convB + (size_t)l * FD, (__half2*)bufA);
    }

    hipMemsetAsync(pool, 0, (size_t)(NG * FD) * sizeof(float) + NG * sizeof(int), stream);
    k_pool<<<(NN + 255) / 256, 256, 0, stream>>>((const __half2*)bufA, batch, pool, cnt);
    k_mlp<<<NG, 128, 0, stream>>>(pool, cnt, linW1, linB1, linW2, linB2, out);
}